// Round 1
// baseline (2744.092 us; speedup 1.0000x reference)
//
#include <hip/hip_runtime.h>
#include <math.h>

#define B_   2
#define S_   2048
#define D_   2048
#define H_   16
#define KVH_ 4
#define HD_  128
#define REP_ 4

// ---------------------------------------------------------------------------
// Kernel 1: fused QKV projection.
// C[4096][3072] = x[4096][2048] @ [Wq | Wk | Wv], scattered to head-major
// Q (B,H,S,HD), K (B,KVH,S,HD), V (B,KVH,S,HD).
// Classic 128x128 tile, BK=8, 256 threads, 8x8 micro-tile per thread.
// ---------------------------------------------------------------------------
__global__ __launch_bounds__(256) void qkv_gemm(
    const float* __restrict__ x,
    const float* __restrict__ Wq, const float* __restrict__ Wk,
    const float* __restrict__ Wv,
    float* __restrict__ Q, float* __restrict__ K, float* __restrict__ V)
{
    const int bm  = blockIdx.x;           // 0..31  (M/128)
    const int bn  = blockIdx.y;           // 0..23  (3072/128)
    const int tid = threadIdx.x;
    const int tx  = tid & 15, ty = tid >> 4;

    const int row0 = bm * 128;
    const int n0   = bn * 128;

    // block-uniform weight-matrix select (tile never crosses a boundary:
    // boundaries 2048/2560 are multiples of 128)
    const float* Wp; int ldw; int wc0;
    if (n0 < 2048)      { Wp = Wq; ldw = 2048; wc0 = n0; }
    else if (n0 < 2560) { Wp = Wk; ldw = 512;  wc0 = n0 - 2048; }
    else                { Wp = Wv; ldw = 512;  wc0 = n0 - 2560; }

    __shared__ float As[8][128];   // [k][m]
    __shared__ float Bs[8][128];   // [k][n]

    float acc[8][8];
    #pragma unroll
    for (int i = 0; i < 8; ++i)
        #pragma unroll
        for (int j = 0; j < 8; ++j) acc[i][j] = 0.0f;

    const int am = tid >> 1;             // 0..127
    const int ak = (tid & 1) * 4;        // 0 or 4
    const int bk = tid >> 5;             // 0..7
    const int bq = (tid & 31) * 4;       // 0..124

    for (int kt = 0; kt < 2048; kt += 8) {
        float4 av = *(const float4*)&x [(size_t)(row0 + am) * 2048 + kt + ak];
        float4 bv = *(const float4*)&Wp[(size_t)(kt + bk) * ldw + wc0 + bq];
        __syncthreads();   // previous iteration's reads complete
        As[ak + 0][am] = av.x; As[ak + 1][am] = av.y;
        As[ak + 2][am] = av.z; As[ak + 3][am] = av.w;
        *(float4*)&Bs[bk][bq] = bv;
        __syncthreads();
        #pragma unroll
        for (int kk = 0; kk < 8; ++kk) {
            float4 a0 = *(const float4*)&As[kk][ty * 8];
            float4 a1 = *(const float4*)&As[kk][ty * 8 + 4];
            float4 b0 = *(const float4*)&Bs[kk][tx * 8];
            float4 b1 = *(const float4*)&Bs[kk][tx * 8 + 4];
            float a[8] = {a0.x,a0.y,a0.z,a0.w,a1.x,a1.y,a1.z,a1.w};
            float b[8] = {b0.x,b0.y,b0.z,b0.w,b1.x,b1.y,b1.z,b1.w};
            #pragma unroll
            for (int i = 0; i < 8; ++i)
                #pragma unroll
                for (int j = 0; j < 8; ++j)
                    acc[i][j] += a[i] * b[j];
        }
    }

    // scatter epilogue — block-uniform branch; 8 cols stay inside one head
    #pragma unroll
    for (int i = 0; i < 8; ++i) {
        int m  = row0 + ty * 8 + i;
        int bb = m >> 11;                // m / 2048
        int s  = m & 2047;
        float4 lo = make_float4(acc[i][0], acc[i][1], acc[i][2], acc[i][3]);
        float4 hi = make_float4(acc[i][4], acc[i][5], acc[i][6], acc[i][7]);
        if (n0 < 2048) {
            int h = n0 >> 7;             // block-uniform
            int d = tx * 8;
            float* dst = Q + (((size_t)bb * H_ + h) * S_ + s) * HD_ + d;
            *(float4*)dst = lo; *(float4*)(dst + 4) = hi;
        } else if (n0 < 2560) {
            int g = (n0 - 2048) >> 7;
            int d = tx * 8;
            float* dst = K + (((size_t)bb * KVH_ + g) * S_ + s) * HD_ + d;
            *(float4*)dst = lo; *(float4*)(dst + 4) = hi;
        } else {
            int g = (n0 - 2560) >> 7;
            int d = tx * 8;
            float* dst = V + (((size_t)bb * KVH_ + g) * S_ + s) * HD_ + d;
            *(float4*)dst = lo; *(float4*)(dst + 4) = hi;
        }
    }
}

// ---------------------------------------------------------------------------
// Kernel 2: RoPE applied in-place to Q (B,H,S,HD) and K (B,KVH,S,HD).
// One thread per (row, d<64) pair.
// ---------------------------------------------------------------------------
__global__ void rope_kernel(float* __restrict__ Q, float* __restrict__ K)
{
    const int NQ = B_ * H_   * S_ * 64;   // 4194304
    const int NK = B_ * KVH_ * S_ * 64;   // 1048576
    int i = blockIdx.x * blockDim.x + threadIdx.x;
    if (i >= NQ + NK) return;

    float* P; int idx;
    if (i < NQ) { P = Q; idx = i; } else { P = K; idx = i - NQ; }

    int d = idx & 63;
    int r = idx >> 6;                 // flat row (bh*S + s)
    int s = r & (S_ - 1);
    size_t base = (size_t)r * HD_;

    float inv = powf(10000.0f, -(float)d * (1.0f / 64.0f));
    float ang = (float)s * inv;
    float c = cosf(ang), sn = sinf(ang);

    float q1 = P[base + d];
    float q2 = P[base + d + 64];
    P[base + d]      = q1 * c - q2 * sn;
    P[base + d + 64] = q2 * c + q1 * sn;
}

// ---------------------------------------------------------------------------
// Kernel 3: fp32 flash attention (causal, GQA).
// Block = 256 threads (16x16), one 64-row Q tile per block.
// Online softmax; O accumulator in registers (4 rows x 8 cols / thread).
// ---------------------------------------------------------------------------
__global__ __launch_bounds__(256) void flash_attn(
    const float* __restrict__ Q, const float* __restrict__ K,
    const float* __restrict__ V, float* __restrict__ att)
{
    const int qt = blockIdx.x;        // 0..31  q-tile
    const int bh = blockIdx.y;        // 0..31
    const int b  = bh >> 4, h = bh & 15;
    const int g  = h >> 2;            // kv head
    const int tid = threadIdx.x;
    const int tx  = tid & 15, ty = tid >> 4;

    const float* Qb = Q + (((size_t)b * H_   + h) * S_) * HD_;
    const float* Kb = K + (((size_t)b * KVH_ + g) * S_) * HD_;
    const float* Vb = V + (((size_t)b * KVH_ + g) * S_) * HD_;

    __shared__ float Qs[64][132];
    __shared__ float Ks[64][132];
    __shared__ float Vs[64][132];
    __shared__ float Ps[64][68];

    const int q0 = qt * 64;

    // stage Q tile once
    for (int t = tid; t < 64 * 32; t += 256) {
        int r = t >> 5, cq = (t & 31) * 4;
        *(float4*)&Qs[r][cq] = *(const float4*)&Qb[(size_t)(q0 + r) * HD_ + cq];
    }

    float m_run[4], l_run[4], o[4][8];
    #pragma unroll
    for (int i = 0; i < 4; ++i) {
        m_run[i] = -1e30f; l_run[i] = 0.0f;
        #pragma unroll
        for (int j = 0; j < 8; ++j) o[i][j] = 0.0f;
    }

    const float scale = 0.08838834764831845f;   // 1/sqrt(128)

    for (int kt = 0; kt <= qt; ++kt) {
        const int k0 = kt * 64;
        __syncthreads();   // prior iteration (and Q staging) complete
        for (int t = tid; t < 64 * 32; t += 256) {
            int r = t >> 5, cq = (t & 31) * 4;
            *(float4*)&Ks[r][cq] = *(const float4*)&Kb[(size_t)(k0 + r) * HD_ + cq];
            *(float4*)&Vs[r][cq] = *(const float4*)&Vb[(size_t)(k0 + r) * HD_ + cq];
        }
        __syncthreads();

        // scores: rows ty*4+i, cols tx*4+j
        float s[4][4] = {{0.f,0.f,0.f,0.f},{0.f,0.f,0.f,0.f},
                         {0.f,0.f,0.f,0.f},{0.f,0.f,0.f,0.f}};
        for (int k = 0; k < HD_; k += 4) {
            float4 qv[4], kv[4];
            #pragma unroll
            for (int i = 0; i < 4; ++i) qv[i] = *(const float4*)&Qs[ty * 4 + i][k];
            #pragma unroll
            for (int j = 0; j < 4; ++j) kv[j] = *(const float4*)&Ks[tx * 4 + j][k];
            #pragma unroll
            for (int i = 0; i < 4; ++i)
                #pragma unroll
                for (int j = 0; j < 4; ++j)
                    s[i][j] += qv[i].x * kv[j].x + qv[i].y * kv[j].y
                             + qv[i].z * kv[j].z + qv[i].w * kv[j].w;
        }

        const bool diag = (kt == qt);
        #pragma unroll
        for (int i = 0; i < 4; ++i) {
            int qi = q0 + ty * 4 + i;
            #pragma unroll
            for (int j = 0; j < 4; ++j) {
                s[i][j] *= scale;
                if (diag && (k0 + tx * 4 + j) > qi) s[i][j] = -1e30f;
            }
        }

        // online softmax (row stats reduced across the 16 tx lanes per ty)
        #pragma unroll
        for (int i = 0; i < 4; ++i) {
            float mt = fmaxf(fmaxf(s[i][0], s[i][1]), fmaxf(s[i][2], s[i][3]));
            #pragma unroll
            for (int off = 1; off < 16; off <<= 1)
                mt = fmaxf(mt, __shfl_xor(mt, off, 16));
            float m_new = fmaxf(m_run[i], mt);
            float alpha = __expf(m_run[i] - m_new);
            float psum = 0.0f;
            #pragma unroll
            for (int j = 0; j < 4; ++j) {
                float p = __expf(s[i][j] - m_new);
                s[i][j] = p;
                psum += p;
            }
            #pragma unroll
            for (int off = 1; off < 16; off <<= 1)
                psum += __shfl_xor(psum, off, 16);
            l_run[i] = l_run[i] * alpha + psum;
            m_run[i] = m_new;
            #pragma unroll
            for (int j = 0; j < 8; ++j) o[i][j] *= alpha;
            #pragma unroll
            for (int j = 0; j < 4; ++j) Ps[ty * 4 + i][tx * 4 + j] = s[i][j];
        }
        __syncthreads();

        // O += P @ V   (cols tx*8 .. tx*8+7)
        for (int j = 0; j < 64; ++j) {
            float4 v0 = *(const float4*)&Vs[j][tx * 8];
            float4 v1 = *(const float4*)&Vs[j][tx * 8 + 4];
            #pragma unroll
            for (int i = 0; i < 4; ++i) {
                float p = Ps[ty * 4 + i][j];
                o[i][0] += p * v0.x; o[i][1] += p * v0.y;
                o[i][2] += p * v0.z; o[i][3] += p * v0.w;
                o[i][4] += p * v1.x; o[i][5] += p * v1.y;
                o[i][6] += p * v1.z; o[i][7] += p * v1.w;
            }
        }
    }

    // epilogue: att is (B, S, H*HD)
    #pragma unroll
    for (int i = 0; i < 4; ++i) {
        float inv_l = 1.0f / l_run[i];
        int srow = q0 + ty * 4 + i;
        float* dst = att + ((size_t)b * S_ + srow) * D_ + h * HD_ + tx * 8;
        #pragma unroll
        for (int j = 0; j < 8; ++j) dst[j] = o[i][j] * inv_l;
    }
}

// ---------------------------------------------------------------------------
// Kernel 4: output projection. out[4096][2048] = att[4096][2048] @ Wo[2048][2048]
// Same 128x128x8 structure as qkv_gemm, contiguous epilogue.
// ---------------------------------------------------------------------------
__global__ __launch_bounds__(256) void out_gemm(
    const float* __restrict__ A, const float* __restrict__ Wo,
    float* __restrict__ C)
{
    const int bm  = blockIdx.x;      // 0..31
    const int bn  = blockIdx.y;      // 0..15
    const int tid = threadIdx.x;
    const int tx  = tid & 15, ty = tid >> 4;
    const int row0 = bm * 128;
    const int n0   = bn * 128;

    __shared__ float As[8][128];
    __shared__ float Bs[8][128];

    float acc[8][8];
    #pragma unroll
    for (int i = 0; i < 8; ++i)
        #pragma unroll
        for (int j = 0; j < 8; ++j) acc[i][j] = 0.0f;

    const int am = tid >> 1;
    const int ak = (tid & 1) * 4;
    const int bk = tid >> 5;
    const int bq = (tid & 31) * 4;

    for (int kt = 0; kt < 2048; kt += 8) {
        float4 av = *(const float4*)&A [(size_t)(row0 + am) * 2048 + kt + ak];
        float4 bv = *(const float4*)&Wo[(size_t)(kt + bk) * 2048 + n0 + bq];
        __syncthreads();
        As[ak + 0][am] = av.x; As[ak + 1][am] = av.y;
        As[ak + 2][am] = av.z; As[ak + 3][am] = av.w;
        *(float4*)&Bs[bk][bq] = bv;
        __syncthreads();
        #pragma unroll
        for (int kk = 0; kk < 8; ++kk) {
            float4 a0 = *(const float4*)&As[kk][ty * 8];
            float4 a1 = *(const float4*)&As[kk][ty * 8 + 4];
            float4 b0 = *(const float4*)&Bs[kk][tx * 8];
            float4 b1 = *(const float4*)&Bs[kk][tx * 8 + 4];
            float a[8] = {a0.x,a0.y,a0.z,a0.w,a1.x,a1.y,a1.z,a1.w};
            float b[8] = {b0.x,b0.y,b0.z,b0.w,b1.x,b1.y,b1.z,b1.w};
            #pragma unroll
            for (int i = 0; i < 8; ++i)
                #pragma unroll
                for (int j = 0; j < 8; ++j)
                    acc[i][j] += a[i] * b[j];
        }
    }

    #pragma unroll
    for (int i = 0; i < 8; ++i) {
        size_t m = (size_t)(row0 + ty * 8 + i);
        float* dst = C + m * 2048 + n0 + tx * 8;
        *(float4*)dst       = make_float4(acc[i][0], acc[i][1], acc[i][2], acc[i][3]);
        *(float4*)(dst + 4) = make_float4(acc[i][4], acc[i][5], acc[i][6], acc[i][7]);
    }
}

// ---------------------------------------------------------------------------
extern "C" void kernel_launch(void* const* d_in, const int* in_sizes, int n_in,
                              void* d_out, int out_size, void* d_ws, size_t ws_size,
                              hipStream_t stream)
{
    const float* x  = (const float*)d_in[0];
    const float* Wq = (const float*)d_in[1];
    const float* Wk = (const float*)d_in[2];
    const float* Wv = (const float*)d_in[3];
    const float* Wo = (const float*)d_in[4];
    float* out = (float*)d_out;

    // workspace layout (floats): Q 8.4M | K 2.1M | V 2.1M | att 8.4M  = 80 MB
    float* Qw  = (float*)d_ws;
    float* Kw  = Qw + (size_t)B_ * H_   * S_ * HD_;
    float* Vw  = Kw + (size_t)B_ * KVH_ * S_ * HD_;
    float* att = Vw + (size_t)B_ * KVH_ * S_ * HD_;

    dim3 g1(32, 24);
    qkv_gemm<<<g1, 256, 0, stream>>>(x, Wq, Wk, Wv, Qw, Kw, Vw);

    const int nrope = (B_ * H_ * S_ * 64) + (B_ * KVH_ * S_ * 64);
    rope_kernel<<<(nrope + 255) / 256, 256, 0, stream>>>(Qw, Kw);

    dim3 g3(32, 32);   // (q-tiles, B*H)
    flash_attn<<<g3, 256, 0, stream>>>(Qw, Kw, Vw, att);

    dim3 g4(32, 16);
    out_gemm<<<g4, 256, 0, stream>>>(att, Wo, out);
}